// Round 3
// baseline (397.027 us; speedup 1.0000x reference)
//
#include <hip/hip_runtime.h>
#include <cmath>

constexpr int KN   = 8;     // spline knots
constexpr int NPAR = 23;    // 3K-1
constexpr int DD   = 32;    // DIM
constexpr int HH   = 32;    // HID
constexpr float BND   = 3.0f;
constexpr float MINBW = 1e-3f;
constexpr float MIND  = 1e-3f;

#define TPB  256
#define ROWS 64      // batch rows per block
#define WPAD 40      // padded row stride (shorts) for bf16 tiles: 80B, 16B-aligned, bank-spread

typedef __attribute__((ext_vector_type(8))) short short8;   // 8 bf16 = 4 VGPRs (MFMA A/B frag)
typedef __attribute__((ext_vector_type(4))) float float4v;  // MFMA C/D frag

__device__ __forceinline__ short f2bf(float f) {
    unsigned u = __float_as_uint(f);
    u += 0x7fffu + ((u >> 16) & 1u);     // round-to-nearest-even
    return (short)(u >> 16);
}

__device__ __forceinline__ float fast_tanh(float x) {
    float ax = fminf(fabsf(x), 15.0f);
    float e  = __expf(2.0f * ax);
    float t  = 1.0f - 2.0f / (e + 1.0f);
    return copysignf(t, x);
}

__device__ __forceinline__ float softplus_f(float v) {
    return fmaxf(v, 0.0f) + log1pf(__expf(-fabsf(v)));
}

// Rational-quadratic spline for one scalar. p[0:8]=W logits, p[8:16]=H logits,
// p[16:23]=D logits (pre double-softplus). Returns z, writes logdet.
__device__ __forceinline__ float rqs_apply(float xv, const float* p, float& ldout) {
    float cw[KN + 1], ch[KN + 1], der[KN + 1];

    // ---- bin widths: Wu = 2B*softmax(p[0:8]); widths = softmax(Wu) pinned ----
    {
        float m = p[0];
#pragma unroll
        for (int k = 1; k < KN; ++k) m = fmaxf(m, p[k]);
        float t0[KN]; float s = 0.f;
#pragma unroll
        for (int k = 0; k < KN; ++k) { t0[k] = __expf(p[k] - m); s += t0[k]; }
        float inv = (2.0f * BND) / s;
        float e2[KN]; float s2 = 0.f;
#pragma unroll
        for (int k = 0; k < KN; ++k) { e2[k] = __expf(inv * (t0[k] - 1.0f)); s2 += e2[k]; }
        float fac = (1.0f - MINBW * KN) / s2;
        float c = 0.f;
        cw[0] = -BND;
#pragma unroll
        for (int k = 0; k < KN; ++k) { c += MINBW + fac * e2[k]; cw[k + 1] = 2.0f * BND * c - BND; }
        cw[KN] = BND;
    }
    // ---- bin heights (same, logits p[8:16]) ----
    {
        float m = p[KN];
#pragma unroll
        for (int k = 1; k < KN; ++k) m = fmaxf(m, p[KN + k]);
        float t0[KN]; float s = 0.f;
#pragma unroll
        for (int k = 0; k < KN; ++k) { t0[k] = __expf(p[KN + k] - m); s += t0[k]; }
        float inv = (2.0f * BND) / s;
        float e2[KN]; float s2 = 0.f;
#pragma unroll
        for (int k = 0; k < KN; ++k) { e2[k] = __expf(inv * (t0[k] - 1.0f)); s2 += e2[k]; }
        float fac = (1.0f - MINBW * KN) / s2;
        float c = 0.f;
        ch[0] = -BND;
#pragma unroll
        for (int k = 0; k < KN; ++k) { c += MINBW + fac * e2[k]; ch[k + 1] = 2.0f * BND * c - BND; }
        ch[KN] = BND;
    }
    der[0] = 1.0f; der[KN] = 1.0f;
#pragma unroll
    for (int k = 1; k < KN; ++k)
        der[k] = MIND + softplus_f(softplus_f(p[2 * KN + k - 1]));

    float xc = fminf(fmaxf(xv, -BND), BND);
    float in_cw = cw[0], in_w = cw[1] - cw[0];
    float in_ch = ch[0], in_h = ch[1] - ch[0];
    float d0 = der[0], d1 = der[1];
#pragma unroll
    for (int k = 1; k < KN; ++k) {
        bool c = (xc >= cw[k]);
        in_cw = c ? cw[k]            : in_cw;
        in_w  = c ? (cw[k+1]-cw[k])  : in_w;
        in_ch = c ? ch[k]            : in_ch;
        in_h  = c ? (ch[k+1]-ch[k])  : in_h;
        d0    = c ? der[k]           : d0;
        d1    = c ? der[k+1]         : d1;
    }

    float th    = (xc - in_cw) / in_w;
    float delta = in_h / in_w;
    float tt    = th * (1.0f - th);
    float th2   = th * th;
    float num   = in_h * (delta * th2 + d0 * tt);
    float den   = delta + (d0 + d1 - 2.0f * delta) * tt;
    float z     = in_ch + num / den;
    float omt   = 1.0f - th;
    float dnum  = delta * delta * (d1 * th2 + 2.0f * delta * tt + d0 * omt * omt);
    float ldv   = __logf(dnum) - 2.0f * __logf(den);

    bool inside = (xv >= -BND) && (xv <= BND);
    ldout = inside ? ldv : 0.0f;
    return inside ? z : xv;
}

// One block: 64 batch rows, loops over all 31 conditioner layers.
// 4 waves; wave w owns M-tile rows [w*16, w*16+16). MFMA 16x16x32 bf16, K=32
// (w1 is causally masked -> K always padded to 32, single code path).
extern "C" __global__ void __launch_bounds__(TPB, 4)
k_nsf(const float* __restrict__ x,
      const float* __restrict__ p0,
      const float* __restrict__ w1, const float* __restrict__ b1,
      const float* __restrict__ w2, const float* __restrict__ b2,
      const float* __restrict__ w3, const float* __restrict__ b3,
      float* __restrict__ zo, float* __restrict__ ldo, int B)
{
    __shared__ __align__(16) short sX [ROWS * WPAD];   // x tile, bf16, [row][k]
    __shared__ __align__(16) short sW1[HH * WPAD];     // W^T [n][k] bf16 (k=31 zero-pad)
    __shared__ __align__(16) short sW2[HH * WPAD];
    __shared__ __align__(16) short sW3[HH * WPAD];     // rows n>=23 zero-pad
    __shared__ __align__(16) short sH [4][16 * WPAD];  // per-wave C->A round-trip
    __shared__ float sP[ROWS * 25];                    // spline params, stride 25 (conflict-free)
    __shared__ float sB1[HH], sB2[HH], sB3[NPAR];

    const int tid  = threadIdx.x;
    const int lane = tid & 63;
    const int wv   = tid >> 6;          // wave 0..3
    const int q    = lane >> 4;         // quad 0..3 -> k = q*8..q*8+7
    const int ln   = lane & 15;         // A-row / B-col within tile
    const long long rowbase = (long long)blockIdx.x * ROWS;

    // one-time zero pads (never overwritten by staging)
    if (tid < 32) sW1[tid * WPAD + 31] = 0;
    for (int i = tid; i < 9 * 32; i += TPB) {
        int n = 23 + (i >> 5), k = i & 31;
        sW3[n * WPAD + k] = 0;
    }
    // stage X as bf16 (coalesced read)
    for (int i = tid; i < ROWS * DD; i += TPB) {
        int r = i >> 5, k = i & 31;
        sX[r * WPAD + k] = f2bf(x[rowbase * DD + i]);
    }

    // dim-0 spline (init_param, wave-uniform broadcast reads)
    float ldacc = 0.0f;
    if (tid < ROWS) {
        float pr[NPAR];
#pragma unroll
        for (int k = 0; k < NPAR; ++k) pr[k] = p0[k];
        float xv = x[(rowbase + tid) * DD + 0];
        float ld;
        zo[(rowbase + tid) * DD + 0] = rqs_apply(xv, pr, ld);
        ldacc = ld;
    }
    __syncthreads();

    for (int ly = 1; ly < DD; ++ly) {
        const int l = ly - 1;
        // ---- stage layer-l weights, transposed to [n][k], bf16 ----
        {
            const float* g1 = w1 + (size_t)l * 992;          // [31][32]
            for (int i = tid; i < 992; i += TPB) {
                int k = i >> 5, n = i & 31;
                sW1[n * WPAD + k] = f2bf(g1[i]);
            }
            const float* g2 = w2 + (size_t)l * 1024;         // [32][32]
            for (int i = tid; i < 1024; i += TPB) {
                int k = i >> 5, n = i & 31;
                sW2[n * WPAD + k] = f2bf(g2[i]);
            }
            const float* g3 = w3 + (size_t)l * 736;          // [32][23]
            for (int i = tid; i < 736; i += TPB) {
                int k = i / 23, n = i - k * 23;
                sW3[n * WPAD + k] = f2bf(g3[i]);
            }
            if (tid < 32)                   sB1[tid]      = b1[(size_t)l * HH + tid];
            else if (tid < 64)              sB2[tid - 32] = b2[(size_t)l * HH + tid - 32];
            else if (tid < 64 + NPAR)       sB3[tid - 64] = b3[(size_t)l * NPAR + tid - 64];
        }
        __syncthreads();

        // ---- H1 = tanh(X @ W1 + b1) : one MFMA per 16x16 tile, K=32 ----
        short8 a = *(const short8*)&sX[(wv * 16 + ln) * WPAD + q * 8];
        float4v c0 = {0.f, 0.f, 0.f, 0.f}, c1 = {0.f, 0.f, 0.f, 0.f};
        {
            short8 bw0 = *(const short8*)&sW1[ln * WPAD + q * 8];
            short8 bw1 = *(const short8*)&sW1[(16 + ln) * WPAD + q * 8];
            c0 = __builtin_amdgcn_mfma_f32_16x16x32_bf16(a, bw0, c0, 0, 0, 0);
            c1 = __builtin_amdgcn_mfma_f32_16x16x32_bf16(a, bw1, c1, 0, 0, 0);
        }
        {
            float bv0 = sB1[ln], bv1 = sB1[16 + ln];
#pragma unroll
            for (int r = 0; r < 4; ++r) {
                int m = q * 4 + r;
                sH[wv][m * WPAD + ln]      = f2bf(fast_tanh(c0[r] + bv0));
                sH[wv][m * WPAD + 16 + ln] = f2bf(fast_tanh(c1[r] + bv1));
            }
        }
        // same-wave LDS write->read is in-order; no barrier needed (per-wave buffer)

        // ---- H2 = tanh(H1 @ W2 + b2) ----
        a = *(const short8*)&sH[wv][ln * WPAD + q * 8];
        float4v d0f = {0.f, 0.f, 0.f, 0.f}, d1f = {0.f, 0.f, 0.f, 0.f};
        {
            short8 bw0 = *(const short8*)&sW2[ln * WPAD + q * 8];
            short8 bw1 = *(const short8*)&sW2[(16 + ln) * WPAD + q * 8];
            d0f = __builtin_amdgcn_mfma_f32_16x16x32_bf16(a, bw0, d0f, 0, 0, 0);
            d1f = __builtin_amdgcn_mfma_f32_16x16x32_bf16(a, bw1, d1f, 0, 0, 0);
        }
        {
            float bv0 = sB2[ln], bv1 = sB2[16 + ln];
#pragma unroll
            for (int r = 0; r < 4; ++r) {
                int m = q * 4 + r;
                sH[wv][m * WPAD + ln]      = f2bf(fast_tanh(d0f[r] + bv0));
                sH[wv][m * WPAD + 16 + ln] = f2bf(fast_tanh(d1f[r] + bv1));
            }
        }

        // ---- P = H2 @ W3 + b3 (N=23, second tile partial) ----
        a = *(const short8*)&sH[wv][ln * WPAD + q * 8];
        float4v e0 = {0.f, 0.f, 0.f, 0.f}, e1 = {0.f, 0.f, 0.f, 0.f};
        {
            short8 bw0 = *(const short8*)&sW3[ln * WPAD + q * 8];
            short8 bw1 = *(const short8*)&sW3[(16 + ln) * WPAD + q * 8];
            e0 = __builtin_amdgcn_mfma_f32_16x16x32_bf16(a, bw0, e0, 0, 0, 0);
            e1 = __builtin_amdgcn_mfma_f32_16x16x32_bf16(a, bw1, e1, 0, 0, 0);
        }
        {
            float bv0 = sB3[ln];
            float bv1 = (ln < 7) ? sB3[16 + ln] : 0.0f;
#pragma unroll
            for (int r = 0; r < 4; ++r) {
                int m = wv * 16 + q * 4 + r;        // block-level row
                sP[m * 25 + ln] = e0[r] + bv0;
                if (ln < 7) sP[m * 25 + 16 + ln] = e1[r] + bv1;
            }
        }
        __syncthreads();

        // ---- spline for dim ly: wave 0 handles all 64 rows (full lanes) ----
        if (tid < ROWS) {
            float pr[NPAR];
#pragma unroll
            for (int k = 0; k < NPAR; ++k) pr[k] = sP[tid * 25 + k];
            float xv = x[(rowbase + tid) * DD + ly];
            float ld;
            zo[(rowbase + tid) * DD + ly] = rqs_apply(xv, pr, ld);
            ldacc += ld;
        }
        // next iteration's weight staging (different buffers) may overlap the
        // tail of the spline; sP/sW overwrite hazards are fenced by the two
        // barriers above.
    }

    if (tid < ROWS) ldo[rowbase + tid] = ldacc;
}

extern "C" void kernel_launch(void* const* d_in, const int* in_sizes, int n_in,
                              void* d_out, int out_size, void* d_ws, size_t ws_size,
                              hipStream_t stream) {
    const float* x  = (const float*)d_in[0];
    const float* p0 = (const float*)d_in[1];
    const float* w1 = (const float*)d_in[2];
    const float* b1 = (const float*)d_in[3];
    const float* w2 = (const float*)d_in[4];
    const float* b2 = (const float*)d_in[5];
    const float* w3 = (const float*)d_in[6];
    const float* b3 = (const float*)d_in[7];

    const int B = in_sizes[0] / DD;            // 65536
    float* zo  = (float*)d_out;
    float* ldo = zo + (size_t)B * DD;

    hipLaunchKernelGGL(k_nsf, dim3(B / ROWS), dim3(TPB), 0, stream,
                       x, p0, w1, b1, w2, b2, w3, b3, zo, ldo, B);
}

// Round 4
// 267.661 us; speedup vs baseline: 1.4833x; 1.4833x over previous
//
#include <hip/hip_runtime.h>
#include <cmath>

constexpr int KN   = 8;     // spline knots
constexpr int NPAR = 23;    // 3K-1
constexpr int DD   = 32;    // DIM
constexpr int HH   = 32;    // HID
constexpr float BND   = 3.0f;
constexpr float MINBW = 1e-3f;
constexpr float MIND  = 1e-3f;

#define TPB   256
#define ROWS  256    // batch rows per block
#define GDIMS 4      // output dims per block (8 groups cover 32)
#define WST   40     // sW row stride (shorts): 80B, 16B-aligned
#define HST   40     // sH row stride (shorts)
#define PST   25     // sP row stride (floats): 25 coprime 32 -> conflict-free

typedef __attribute__((ext_vector_type(8))) short short8;   // 8 bf16 (MFMA A/B frag)
typedef __attribute__((ext_vector_type(4))) float float4v;  // MFMA C/D frag

__device__ __forceinline__ short f2bf(float f) {
    unsigned u = __float_as_uint(f);
    u += 0x7fffu + ((u >> 16) & 1u);     // round-to-nearest-even
    return (short)(u >> 16);
}

__device__ __forceinline__ float fast_tanh(float x) {
    float ax = fminf(fabsf(x), 15.0f);
    float e  = __expf(2.0f * ax);
    float t  = 1.0f - 2.0f / (e + 1.0f);
    return copysignf(t, x);
}

__device__ __forceinline__ float softplus_f(float v) {
    return fmaxf(v, 0.0f) + log1pf(__expf(-fabsf(v)));
}

// Rational-quadratic spline for one scalar. p[0:8]=W logits, p[8:16]=H logits,
// p[16:23]=D logits (pre double-softplus). Returns z, writes logdet.
__device__ __forceinline__ float rqs_apply(float xv, const float* p, float& ldout) {
    float cw[KN + 1], ch[KN + 1], der[KN + 1];
    {
        float m = p[0];
#pragma unroll
        for (int k = 1; k < KN; ++k) m = fmaxf(m, p[k]);
        float t0[KN]; float s = 0.f;
#pragma unroll
        for (int k = 0; k < KN; ++k) { t0[k] = __expf(p[k] - m); s += t0[k]; }
        float inv = (2.0f * BND) / s;
        float e2[KN]; float s2 = 0.f;
#pragma unroll
        for (int k = 0; k < KN; ++k) { e2[k] = __expf(inv * (t0[k] - 1.0f)); s2 += e2[k]; }
        float fac = (1.0f - MINBW * KN) / s2;
        float c = 0.f;
        cw[0] = -BND;
#pragma unroll
        for (int k = 0; k < KN; ++k) { c += MINBW + fac * e2[k]; cw[k + 1] = 2.0f * BND * c - BND; }
        cw[KN] = BND;
    }
    {
        float m = p[KN];
#pragma unroll
        for (int k = 1; k < KN; ++k) m = fmaxf(m, p[KN + k]);
        float t0[KN]; float s = 0.f;
#pragma unroll
        for (int k = 0; k < KN; ++k) { t0[k] = __expf(p[KN + k] - m); s += t0[k]; }
        float inv = (2.0f * BND) / s;
        float e2[KN]; float s2 = 0.f;
#pragma unroll
        for (int k = 0; k < KN; ++k) { e2[k] = __expf(inv * (t0[k] - 1.0f)); s2 += e2[k]; }
        float fac = (1.0f - MINBW * KN) / s2;
        float c = 0.f;
        ch[0] = -BND;
#pragma unroll
        for (int k = 0; k < KN; ++k) { c += MINBW + fac * e2[k]; ch[k + 1] = 2.0f * BND * c - BND; }
        ch[KN] = BND;
    }
    der[0] = 1.0f; der[KN] = 1.0f;
#pragma unroll
    for (int k = 1; k < KN; ++k)
        der[k] = MIND + softplus_f(softplus_f(p[2 * KN + k - 1]));

    float xc = fminf(fmaxf(xv, -BND), BND);
    float in_cw = cw[0], in_w = cw[1] - cw[0];
    float in_ch = ch[0], in_h = ch[1] - ch[0];
    float d0 = der[0], d1 = der[1];
#pragma unroll
    for (int k = 1; k < KN; ++k) {
        bool c = (xc >= cw[k]);
        in_cw = c ? cw[k]            : in_cw;
        in_w  = c ? (cw[k+1]-cw[k])  : in_w;
        in_ch = c ? ch[k]            : in_ch;
        in_h  = c ? (ch[k+1]-ch[k])  : in_h;
        d0    = c ? der[k]           : d0;
        d1    = c ? der[k+1]         : d1;
    }

    float th    = (xc - in_cw) / in_w;
    float delta = in_h / in_w;
    float tt    = th * (1.0f - th);
    float th2   = th * th;
    float num   = in_h * (delta * th2 + d0 * tt);
    float den   = delta + (d0 + d1 - 2.0f * delta) * tt;
    float z     = in_ch + num / den;
    float omt   = 1.0f - th;
    float dnum  = delta * delta * (d1 * th2 + 2.0f * delta * tt + d0 * omt * omt);
    float ldv   = __logf(dnum) - 2.0f * __logf(den);

    bool inside = (xv >= -BND) && (xv <= BND);
    ldout = inside ? ldv : 0.0f;
    return inside ? z : xv;
}

// Block: 256 rows x 4 output dims (blockIdx.y = group). 4 waves, wave wv owns
// rows [64wv, 64wv+64) = 4 M-tiles of 16. MFMA 16x16x32 bf16, K=32 (w1 causal
// rows are zero, K padded). sP is per-wave private -> spline needs no barrier.
extern "C" __global__ void __launch_bounds__(TPB, 4)
k_nsf(const float* __restrict__ x,
      const float* __restrict__ p0,
      const float* __restrict__ w1, const float* __restrict__ b1,
      const float* __restrict__ w2, const float* __restrict__ b2,
      const float* __restrict__ w3, const float* __restrict__ b3,
      float* __restrict__ zo, float* __restrict__ ldo, int B)
{
    __shared__ __align__(16) short sW1[HH * WST];     // W^T [n][k] bf16, k=31 zero-pad
    __shared__ __align__(16) short sW2[HH * WST];
    __shared__ __align__(16) short sW3[HH * WST];     // rows n>=23 zero-pad
    __shared__ __align__(16) short sH [4][16 * HST];  // per-wave C->A round-trip
    __shared__ float sP[ROWS * PST];                  // per-wave-private P rows
    __shared__ float sB1[HH], sB2[HH], sB3[24];

    const int tid  = threadIdx.x;
    const int lane = tid & 63;
    const int wv   = tid >> 6;
    const int q    = lane >> 4;
    const int ln   = lane & 15;
    const int g    = blockIdx.y;
    const long long rowbase = (long long)blockIdx.x * ROWS;
    const long long row = rowbase + tid;     // this thread's spline row

    // one-time zero pads (locations never re-staged; first barrier orders them)
    if (tid < HH) sW1[tid * WST + 31] = 0;
    for (int i = tid; i < 9 * 32; i += TPB) {
        int n = 23 + (i >> 5), k = i & 31;
        sW3[n * WST + k] = 0;
    }

    float zreg[GDIMS];
    float ldacc = 0.0f;

    const int ly0 = GDIMS * g;
    for (int ly = ly0; ly < ly0 + GDIMS; ++ly) {
        if (ly == 0) {
            // init_param spline (wave-uniform p0 reads)
            float pr[NPAR];
#pragma unroll
            for (int k = 0; k < NPAR; ++k) pr[k] = p0[k];
            float xv = x[row * DD + 0];
            float ld;
            zreg[0] = rqs_apply(xv, pr, ld);
            ldacc += ld;
            continue;
        }
        const int l = ly - 1;
        // ---- stage layer-l weights (transposed [n][k], bf16) + biases ----
        {
            const float* g1 = w1 + (size_t)l * 992;          // [31][32]
            for (int i = tid; i < 992; i += TPB) {
                int k = i >> 5, n = i & 31;
                sW1[n * WST + k] = f2bf(g1[i]);
            }
            const float* g2 = w2 + (size_t)l * 1024;         // [32][32]
            for (int i = tid; i < 1024; i += TPB) {
                int k = i >> 5, n = i & 31;
                sW2[n * WST + k] = f2bf(g2[i]);
            }
            const float* g3 = w3 + (size_t)l * 736;          // [32][23]
            for (int i = tid; i < 736; i += TPB) {
                int k = i / 23, n = i - k * 23;
                sW3[n * WST + k] = f2bf(g3[i]);
            }
            if (tid < HH)                 sB1[tid]      = b1[(size_t)l * HH + tid];
            else if (tid < 2 * HH)        sB2[tid - HH] = b2[(size_t)l * HH + tid - HH];
            else if (tid < 2 * HH + NPAR) sB3[tid - 64] = b3[(size_t)l * NPAR + tid - 64];
        }
        __syncthreads();

        // hoist B-frags + biases (reused across 4 M-tiles)
        short8 w1b0 = *(const short8*)&sW1[ln * WST + q * 8];
        short8 w1b1 = *(const short8*)&sW1[(16 + ln) * WST + q * 8];
        short8 w2b0 = *(const short8*)&sW2[ln * WST + q * 8];
        short8 w2b1 = *(const short8*)&sW2[(16 + ln) * WST + q * 8];
        short8 w3b0 = *(const short8*)&sW3[ln * WST + q * 8];
        short8 w3b1 = *(const short8*)&sW3[(16 + ln) * WST + q * 8];
        float bv1a = sB1[ln], bv1b = sB1[16 + ln];
        float bv2a = sB2[ln], bv2b = sB2[16 + ln];
        float bv3a = sB3[ln], bv3b = (ln < 7) ? sB3[16 + ln] : 0.0f;

#pragma unroll
        for (int t = 0; t < 4; ++t) {
            const int m0 = 64 * wv + 16 * t;
            // ---- A1 directly from global x (fp32 -> bf16 in regs) ----
            const float4* xp = (const float4*)(x + (rowbase + m0 + ln) * DD + q * 8);
            float4 u = xp[0], v = xp[1];
            short8 a;
            a[0] = f2bf(u.x); a[1] = f2bf(u.y); a[2] = f2bf(u.z); a[3] = f2bf(u.w);
            a[4] = f2bf(v.x); a[5] = f2bf(v.y); a[6] = f2bf(v.z); a[7] = f2bf(v.w);

            float4v c0 = {0.f,0.f,0.f,0.f}, c1 = {0.f,0.f,0.f,0.f};
            c0 = __builtin_amdgcn_mfma_f32_16x16x32_bf16(a, w1b0, c0, 0, 0, 0);
            c1 = __builtin_amdgcn_mfma_f32_16x16x32_bf16(a, w1b1, c1, 0, 0, 0);
#pragma unroll
            for (int r = 0; r < 4; ++r) {
                int m = q * 4 + r;
                sH[wv][m * HST + ln]      = f2bf(fast_tanh(c0[r] + bv1a));
                sH[wv][m * HST + 16 + ln] = f2bf(fast_tanh(c1[r] + bv1b));
            }
            // same-wave LDS write->read: compiler orders via lgkmcnt
            a = *(const short8*)&sH[wv][ln * HST + q * 8];
            float4v d0 = {0.f,0.f,0.f,0.f}, d1 = {0.f,0.f,0.f,0.f};
            d0 = __builtin_amdgcn_mfma_f32_16x16x32_bf16(a, w2b0, d0, 0, 0, 0);
            d1 = __builtin_amdgcn_mfma_f32_16x16x32_bf16(a, w2b1, d1, 0, 0, 0);
#pragma unroll
            for (int r = 0; r < 4; ++r) {
                int m = q * 4 + r;
                sH[wv][m * HST + ln]      = f2bf(fast_tanh(d0[r] + bv2a));
                sH[wv][m * HST + 16 + ln] = f2bf(fast_tanh(d1[r] + bv2b));
            }
            a = *(const short8*)&sH[wv][ln * HST + q * 8];
            float4v e0 = {0.f,0.f,0.f,0.f}, e1 = {0.f,0.f,0.f,0.f};
            e0 = __builtin_amdgcn_mfma_f32_16x16x32_bf16(a, w3b0, e0, 0, 0, 0);
            e1 = __builtin_amdgcn_mfma_f32_16x16x32_bf16(a, w3b1, e1, 0, 0, 0);
#pragma unroll
            for (int r = 0; r < 4; ++r) {
                int m = m0 + q * 4 + r;
                sP[m * PST + ln] = e0[r] + bv3a;
                if (ln < 7) sP[m * PST + 16 + ln] = e1[r] + bv3b;
            }
        }

        // ---- spline: thread tid -> row tid; sP rows written by OWN wave ----
        {
            float pr[NPAR];
#pragma unroll
            for (int k = 0; k < NPAR; ++k) pr[k] = sP[tid * PST + k];
            float xv = x[row * DD + ly];
            float ld;
            zreg[ly - ly0] = rqs_apply(xv, pr, ld);
            ldacc += ld;
        }
        __syncthreads();   // protect sW before next layer's staging
    }

    // coalesced z write: 4 contiguous dims per thread, 16B aligned
    float4 zv = make_float4(zreg[0], zreg[1], zreg[2], zreg[3]);
    *(float4*)(zo + row * DD + ly0) = zv;
    unsafeAtomicAdd(&ldo[row], ldacc);
}

extern "C" void kernel_launch(void* const* d_in, const int* in_sizes, int n_in,
                              void* d_out, int out_size, void* d_ws, size_t ws_size,
                              hipStream_t stream) {
    const float* x  = (const float*)d_in[0];
    const float* p0 = (const float*)d_in[1];
    const float* w1 = (const float*)d_in[2];
    const float* b1 = (const float*)d_in[3];
    const float* w2 = (const float*)d_in[4];
    const float* b2 = (const float*)d_in[5];
    const float* w3 = (const float*)d_in[6];
    const float* b3 = (const float*)d_in[7];

    const int B = in_sizes[0] / DD;            // 65536
    float* zo  = (float*)d_out;
    float* ldo = zo + (size_t)B * DD;

    hipMemsetAsync(ldo, 0, (size_t)B * sizeof(float), stream);
    hipLaunchKernelGGL(k_nsf, dim3(B / ROWS, DD / GDIMS), dim3(TPB), 0, stream,
                       x, p0, w1, b1, w2, b2, w3, b3, zo, ldo, B);
}